// Round 2
// baseline (90.556 us; speedup 1.0000x reference)
//
#include <hip/hip_runtime.h>

#define BLOCK 8
#define NGRID 512

typedef float v2f __attribute__((ext_vector_type(2)));

// ---------------------------------------------------------------------------
// Compile-time replication of
//   np.random.RandomState(0).choice(np.array([1.0,3.0],f32), size=(512,8))
// (MT19937 legacy scalar seeding, one 32-bit draw per value, value = draw&1).
// Bit i of pattern byte = element i: g[i] = bit ? 3.0f : 1.0f.
// Dedup (first occurrence) is argmax-neutral. kenc = 255 - dedup_index, so
// "ties -> max kenc" == numpy first-max. Scan order = bit-reversed ascending
// (maximizes shared low-bit spine prefixes); selection is order-independent.
// ---------------------------------------------------------------------------
struct Sched {
  int nd;                      // distinct patterns (~222)
  unsigned char kpat[256];     // kenc -> pattern byte (epilogue gather)
  unsigned char dfs_pat[256];  // scan ordinal -> pattern byte
  unsigned char dfs_ken[256];  // scan ordinal -> kenc
  unsigned char lowbit[256];   // ordinal -> lowest differing bit vs prev (0 for j=0)
  unsigned char csn[32];       // chunk -> member count (chunks of 8)
  unsigned char cslot[32][8];  // chunk, i -> slot (ordinal & 7), kenc-ascending
  unsigned char cken[32][8];   // chunk, i -> kenc,                kenc-ascending
};

constexpr unsigned char bitrev8c(unsigned v) {
  unsigned r = 0;
  for (int i = 0; i < 8; ++i) r |= ((v >> i) & 1u) << (7 - i);
  return (unsigned char)r;
}
constexpr int popcount8c(int v) {
  int p = 0;
  for (int i = 0; i < 8; ++i) p += (v >> i) & 1;
  return p;
}
constexpr int ctz8c(int v) {
  for (int i = 0; i < 8; ++i) if ((v >> i) & 1) return i;
  return 0;
}

constexpr Sched make_sched() {
  Sched t{};
  bool exists[256] = {};
  unsigned char kenc[256] = {};
  // --- MT19937, numpy legacy scalar seed 0 ---
  unsigned mt[624] = {};
  {
    unsigned s = 0u;
    for (int i = 0; i < 624; ++i) {
      mt[i] = s;
      s = 1812433253u * (s ^ (s >> 30)) + (unsigned)(i + 1);
    }
  }
  int pos = 624;
  int nd = 0;
  for (int j = 0; j < NGRID; ++j) {
    unsigned char b = 0;
    for (int i = 0; i < BLOCK; ++i) {
      if (pos == 624) {
        for (int k = 0; k < 624; ++k) {
          int k1 = (k + 1 < 624) ? k + 1 : 0;
          int k397 = (k + 397 < 624) ? k + 397 : k + 397 - 624;
          unsigned y = (mt[k] & 0x80000000u) | (mt[k1] & 0x7fffffffu);
          unsigned v = mt[k397] ^ (y >> 1);
          if (y & 1u) v ^= 0x9908b0dfu;
          mt[k] = v;
        }
        pos = 0;
      }
      unsigned y = mt[pos++];
      y ^= y >> 11;
      y ^= (y << 7) & 0x9d2c5680u;
      y ^= (y << 15) & 0xefc60000u;
      y ^= y >> 18;
      if (y & 1u) b |= (unsigned char)(1u << i);
    }
    if (!exists[b]) {
      exists[b] = true;
      kenc[b] = (unsigned char)(255 - nd);
      t.kpat[255 - nd] = b;
      ++nd;
    }
  }
  t.nd = nd;
  // --- scan order: bit-reversed ascending ---
  int m = 0;
  for (int r = 0; r < 256; ++r) {
    unsigned char b = bitrev8c((unsigned)r);
    if (exists[b]) {
      t.dfs_pat[m] = b;
      t.dfs_ken[m] = kenc[b];
      ++m;
    }
  }
  t.lowbit[0] = 0;
  for (int j = 1; j < nd; ++j)
    t.lowbit[j] = (unsigned char)ctz8c(t.dfs_pat[j] ^ t.dfs_pat[j - 1]);
  // --- chunks of 8, members sorted by kenc ascending (insertion sort) ---
  int nc = (nd + 7) / 8;
  for (int c = 0; c < nc; ++c) {
    int n = nd - 8 * c; if (n > 8) n = 8;
    t.csn[c] = (unsigned char)n;
    unsigned char sl[8] = {}, ke[8] = {};
    for (int i = 0; i < n; ++i) { sl[i] = (unsigned char)i; ke[i] = t.dfs_ken[8 * c + i]; }
    for (int i = 1; i < n; ++i) {
      unsigned char ks = ke[i], ss = sl[i];
      int p = i - 1;
      while (p >= 0 && ke[p] > ks) { ke[p + 1] = ke[p]; sl[p + 1] = sl[p]; --p; }
      ke[p + 1] = ks; sl[p + 1] = ss;
    }
    for (int i = 0; i < n; ++i) { t.cslot[c][i] = sl[i]; t.cken[c][i] = ke[i]; }
  }
  return t;
}

constexpr Sched SC = make_sched();
constexpr int ND = SC.nd;
static_assert(ND > 0 && ND <= 256, "sanity");

// chunk-local winner index -> kenc, packed 8 bytes into a u64 (compile time)
constexpr unsigned long long pack_klut(int c) {
  unsigned long long v = 0ull;
  for (int i = 0; i < 8; ++i)
    v |= (unsigned long long)SC.cken[c][i] << (8 * i);
  return v;
}

// epilogue gather table: kenc -> pattern byte (L1-resident)
__device__ __constant__ const unsigned char g_pat[256] = {
#define P1(z) SC.kpat[z]
#define P8(z) P1(z), P1(z+1), P1(z+2), P1(z+3), P1(z+4), P1(z+5), P1(z+6), P1(z+7)
#define P64(z) P8(z), P8(z+8), P8(z+16), P8(z+24), P8(z+32), P8(z+40), P8(z+48), P8(z+56)
    P64(0), P64(64), P64(128), P64(192)
#undef P64
#undef P8
#undef P1
};

// ---------------------------------------------------------------------------
// PACKED trie scan step, ordinal J. Two independent weight blocks ride in the
// two halves of each v2f; spine FMAs / d*d / score math lower to
// v_pk_fma_f32 / v_pk_mul_f32 / v_pk_add_f32 (gfx90a+ packed FP32, IEEE
// per-half == scalar ops => scores bit-identical to the proven scalar
// kernel). Selection / tie-break runs scalar per half, logic unchanged.
// ---------------------------------------------------------------------------
template <int J>
struct Step {
  static __device__ __forceinline__ void run(const v2f (&a)[BLOCK], v2f (&sp)[9],
                                             v2f (&scs)[8], float (&gb)[2], int (&gk)[2]) {
    constexpr int pat = SC.dfs_pat[J];
    constexpr int p0 = (J == 0) ? 0 : SC.lowbit[J];
#pragma unroll
    for (int l = 0; l < 8; ++l) {
      if (l >= p0) {
        if ((pat >> l) & 1)
          sp[l + 1] = __builtin_elementwise_fma(a[l], v2f{3.0f, 3.0f}, sp[l]);
        else
          sp[l + 1] = sp[l] + a[l];
      }
    }
    v2f d = sp[8];
    v2f dd = d * d;
    constexpr int pc = popcount8c(pat);
    v2f sc;
    if constexpr (pc == 0)      sc = dd * v2f{0.125f, 0.125f};       // /8   exact
    else if constexpr (pc == 1) sc = dd * v2f{0.0625f, 0.0625f};     // /16  exact
    else if constexpr (pc == 3) sc = dd * v2f{0.03125f, 0.03125f};   // /32  exact
    else if constexpr (pc == 7) sc = dd * v2f{0.015625f, 0.015625f}; // /64  exact
    else {
      constexpr float nf = (float)(8 * (1 + pc));
      constexpr float rcf = 1.0f / nf;                 // RN reciprocal (compile time)
      v2f q0 = dd * v2f{rcf, rcf};
      v2f r = __builtin_elementwise_fma(v2f{-nf, -nf}, q0, dd);  // exact residual
      sc = __builtin_elementwise_fma(r, v2f{rcf, rcf}, q0);      // Markstein: == fl32(dd/nf)
    }
    scs[J & 7] = sc;

    if constexpr (((J & 7) == 7) || (J == ND - 1)) {
      constexpr int c = J >> 3;
      constexpr int n = SC.csn[c];
      constexpr unsigned long long klut = pack_klut(c);
#pragma unroll
      for (int h = 0; h < 2; ++h) {
        float cm;
        if constexpr (n == 8) {
          cm = __builtin_fmaxf(
              __builtin_fmaxf(__builtin_fmaxf(scs[0][h], scs[1][h]),
                              __builtin_fmaxf(scs[2][h], scs[3][h])),
              __builtin_fmaxf(__builtin_fmaxf(scs[4][h], scs[5][h]),
                              __builtin_fmaxf(scs[6][h], scs[7][h])));
        } else {
          cm = scs[0][h];
#pragma unroll
          for (int i = 1; i < n; ++i) cm = __builtin_fmaxf(cm, scs[i][h]);
        }
        int ck = 0;
#pragma unroll
        for (int i = 0; i < n; ++i)   // kenc ascending: last write = min original k
          ck = (scs[SC.cslot[c][i]][h] == cm) ? i : ck;  // i is an inline constant
        int kenc = (int)((unsigned)(klut >> (ck << 3)) & 0xFFu);
        bool r = (cm > gb[h]) || ((cm == gb[h]) && (kenc > gk[h]));
        gb[h] = r ? cm : gb[h];
        gk[h] = r ? kenc : gk[h];
      }
    }
    if (J + 1 < ND) {
      if constexpr (J + 1 < ND) Step<J + 1>::run(a, sp, scs, gb, gk);
    }
  }
};

// 2 blocks/thread, packed-f32 scan. launch_bounds(256,4): 128-VGPR cap;
// est. live set ~70 (a2:16, sp:18, scs:16, gb/gk/sbits/addr/temps ~20).
// Grid: 1024 WGs = 4 WG/CU = 4 waves/SIMD, matching total work exactly.
__global__ __launch_bounds__(256, 4) void _IQ2XSQuantWeight_12945031430379_kernel(
    const float* __restrict__ w, float* __restrict__ out, int nt) {
  int t = blockIdx.x * blockDim.x + threadIdx.x;
  if (t >= nt) return;

  // two adjacent 8-elem blocks per thread: 64 contiguous bytes per lane
  const float4* wp = reinterpret_cast<const float4*>(w) + (size_t)4 * t;
  float4 A0 = wp[0];
  float4 A1 = wp[1];
  float4 B0 = wp[2];
  float4 B1 = wp[3];
  float wvA[BLOCK] = {A0.x, A0.y, A0.z, A0.w, A1.x, A1.y, A1.z, A1.w};
  float wvB[BLOCK] = {B0.x, B0.y, B0.z, B0.w, B1.x, B1.y, B1.z, B1.w};

  // |w| packed per half + one sign-bit mask per half (epilogue reconstructs
  // wv bit-exactly: |w| OR signbit == original bits).
  v2f a[BLOCK];
  unsigned int sb[2] = {0u, 0u};
#pragma unroll
  for (int i = 0; i < BLOCK; ++i) {
    unsigned int ua = __float_as_uint(wvA[i]);
    unsigned int ub = __float_as_uint(wvB[i]);
    sb[0] |= (ua >> 31) << i;
    sb[1] |= (ub >> 31) << i;
    a[i] = v2f{__uint_as_float(ua & 0x7fffffffu), __uint_as_float(ub & 0x7fffffffu)};
  }

  v2f sp[9];
  sp[0] = v2f{0.0f, 0.0f};
  v2f scs[8];
  float gb[2] = {-1.0f, -1.0f};
  int gk[2] = {0, 0};
  Step<0>::run(a, sp, scs, gb, gk);

  // ---- epilogue: per half, bit-identical to the proven scalar kernel ----
  float4 o4[4];
#pragma unroll
  for (int h = 0; h < 2; ++h) {
    unsigned int bits = (unsigned int)g_pat[gk[h]];  // divergent 1-byte gather, L1

    float q[BLOCK];
#pragma unroll
    for (int i = 0; i < BLOCK; ++i) q[i] = ((bits >> i) & 1u) ? 3.0f : 1.0f;

    float p[BLOCK];
#pragma unroll
    for (int i = 0; i < BLOCK; ++i) p[i] = a[i][h] * q[i];
    float num = ((p[0] + p[1]) + (p[2] + p[3])) + ((p[4] + p[5]) + (p[6] + p[7]));

    int popc = __popc(bits);
    float normf = (float)(8 + (popc << 3));
    float scale = num / normf;                     // IEEE CR f32 divide (once/half)

    float o[BLOCK];
#pragma unroll
    for (int i = 0; i < BLOCK; ++i) {
      // bit-exact reconstruction of wv[i]
      float wvi = __uint_as_float(__float_as_uint(a[i][h]) | (((sb[h] >> i) & 1u) << 31));
      float sg = (wvi > 0.0f) ? 1.0f : ((wvi < 0.0f) ? -1.0f : 0.0f);
      float deq = (scale * q[i]) * sg;
      o[i] = wvi + (deq - wvi);                    // w + stop_gradient(deq - w)
    }
    o4[2 * h + 0] = float4{o[0], o[1], o[2], o[3]};
    o4[2 * h + 1] = float4{o[4], o[5], o[6], o[7]};
  }

  float4* op = reinterpret_cast<float4*>(out) + (size_t)4 * t;
  op[0] = o4[0];
  op[1] = o4[1];
  op[2] = o4[2];
  op[3] = o4[3];
}

extern "C" void kernel_launch(void* const* d_in, const int* in_sizes, int n_in,
                              void* d_out, int out_size, void* d_ws, size_t ws_size,
                              hipStream_t stream) {
  (void)n_in; (void)d_ws; (void)ws_size; (void)out_size;
  const float* w = (const float*)d_in[0];
  float* out = (float*)d_out;
  int n = in_sizes[0];
  int nb = n / BLOCK;      // 8-elem quant blocks
  int nt = nb / 2;         // 2 blocks per thread (nb is even: 524288)
  int threads = 256;
  int blocks = (nt + threads - 1) / threads;
  _IQ2XSQuantWeight_12945031430379_kernel<<<blocks, threads, 0, stream>>>(w, out, nt);
}